// Round 9
// baseline (201.401 us; speedup 1.0000x reference)
//
#include <hip/hip_runtime.h>

#define H 1024
#define E 8
#define BLK 512
#define CAP 5120       // int(1.25 * 4096 * 8 / 8)
#define FBLK 1024
#define TPW 4          // tokens per wave

typedef float f32x4 __attribute__((ext_vector_type(4)));

// ---------------------------------------------------------------------------
// Kernel 1: contiguous-stream GEMV — 32 waves/CU occupancy variant.
// R6/R7/R8 (three different per-wave schedules at 16 waves/CU) all landed at
// total 197-199us -> per-wave schedule is NOT the limiter; no pipe >45%
// (HBM/CU 27us, LDS 10us, VALU 8us vs router ~61us) -> latency/TLP regime.
// Last untested lever: occupancy. All clean kernels ran 16 waves/CU
// (LDS 33KB -> 4 blk/CU at BLK=256; VGPR cap 128 -> 4 waves/SIMD).
// THIS ROUND: BLK=512 + __launch_bounds__(512,4):
//  * LDS 33KB -> 4 blocks/CU x 8 waves = 32 waves/CU (2x TLP);
//  * session rule (R0-R5): VGPR cap = 256/arg2 -> arg2=4 gives cap 64,
//    exactly the 8-waves/SIMD requirement;
//  * lean ~55-reg design: TPW=4, 2-token micro-steps, q-granular A
//    streaming (a0,a1 + n0,n1 prefetch = 16 regs, not 32-64), per-expert
//    w reads (wv transient small), acc 16, addr ~12. No spill at cap 64.
//  * w LDS reuse across the token pair kept -> LDS traffic unchanged.
// Design constants (validated R3-R8: 0 bank conflicts when clean):
//  - w in LDS 32KB; lane l reads (e*1024+q*256+4l): conflict-free b128.
//  - hs loads 1KB-contiguous per wave (lane l owns floats {4l+256q}).
//  - reduce-scatter -> lane 8g+e holds logit(token g, expert e), g<4 own.
//  - group-of-8 softmax/top2; stores 1 dword/lane, 128B contiguous (g<4).
// ---------------------------------------------------------------------------
__global__ __launch_bounds__(BLK, 4) void router_kernel(
    const float* __restrict__ hs,
    const float* __restrict__ rw,
    float* __restrict__ dispatch,
    float* __restrict__ probs_out,
    float* __restrict__ partial)   // [16][nb] slot-major
{
    __shared__ float w_lds[E * H];   // 32 KB
    __shared__ float red[8][16];

    const int tid  = threadIdx.x;
    const int wave = tid >> 6;       // 0..7
    const int lane = tid & 63;
    const int g    = lane >> 3;      // token group within wave (0..7; g<4 own)
    const int eo   = lane & 7;       // owned expert
    const size_t tok0 = ((size_t)blockIdx.x * (BLK / 64) + wave) * TPW;
    const float* hp = hs + tok0 * H + 4 * lane;

    // first pair, q=0 slices issued before w staging (overlap HBM with it)
    f32x4 a0 = *(const f32x4*)(hp);
    f32x4 a1 = *(const f32x4*)(hp + H);

    for (int i = tid; i < E * H / 4; i += BLK)
        ((f32x4*)w_lds)[i] = ((const f32x4*)rw)[i];
    __syncthreads();

    const int b0 = lane & 1, b1 = (lane >> 1) & 1, b2 = (lane >> 2) & 1;

    // reduce-scatter over the 8-expert set (inputs by value, all-SSA).
    // Output: full dot for expert (lane&7), replicated over 8-lane groups.
    auto rscatter = [&](float a0_, float a1_, float a2_, float a3_,
                        float a4_, float a5_, float a6_, float a7_) -> float {
        float r0 = b0 ? a1_ : a0_, s0 = b0 ? a0_ : a1_;
        float r1 = b0 ? a3_ : a2_, s1 = b0 ? a2_ : a3_;
        float r2 = b0 ? a5_ : a4_, s2 = b0 ? a4_ : a5_;
        float r3 = b0 ? a7_ : a6_, s3 = b0 ? a6_ : a7_;
        r0 += __shfl_xor(s0, 1); r1 += __shfl_xor(s1, 1);
        r2 += __shfl_xor(s2, 1); r3 += __shfl_xor(s3, 1);
        float t0 = b1 ? r1 : r0, u0 = b1 ? r0 : r1;
        float t1 = b1 ? r3 : r2, u1 = b1 ? r2 : r3;
        t0 += __shfl_xor(u0, 2); t1 += __shfl_xor(u1, 2);
        float v = b2 ? t1 : t0, x = b2 ? t0 : t1;
        v += __shfl_xor(x, 4);
        v += __shfl_xor(v, 8);
        v += __shfl_xor(v, 16);
        v += __shfl_xor(v, 32);
        return v;                 // logit for expert 4*b2+2*b1+b0 = lane&7
    };

    float mylog = 0.f;            // latched logit for (token tok0+g, expert eo)

#pragma unroll
    for (int p = 0; p < 2; ++p) {   // token pairs (2p, 2p+1)
        float acc0[E], acc1[E];
#pragma unroll
        for (int e = 0; e < E; ++e) { acc0[e] = 0.f; acc1[e] = 0.f; }

#pragma unroll
        for (int q = 0; q < 4; ++q) {
            // prefetch next q-slice (or next pair's q=0) before consuming
            f32x4 n0, n1;
            if (q < 3) {
                n0 = *(const f32x4*)(hp + (2 * p) * H + (q + 1) * 256);
                n1 = *(const f32x4*)(hp + (2 * p + 1) * H + (q + 1) * 256);
            } else if (p == 0) {
                n0 = *(const f32x4*)(hp + 2 * H);
                n1 = *(const f32x4*)(hp + 3 * H);
            }
            const float* wb = w_lds + q * 256 + 4 * lane;
#pragma unroll
            for (int e = 0; e < E; ++e) {
                const f32x4 wv = *(const f32x4*)(wb + e * H);
                acc0[e] = fmaf(a0[0], wv[0], acc0[e]);
                acc0[e] = fmaf(a0[1], wv[1], acc0[e]);
                acc0[e] = fmaf(a0[2], wv[2], acc0[e]);
                acc0[e] = fmaf(a0[3], wv[3], acc0[e]);
                acc1[e] = fmaf(a1[0], wv[0], acc1[e]);
                acc1[e] = fmaf(a1[1], wv[1], acc1[e]);
                acc1[e] = fmaf(a1[2], wv[2], acc1[e]);
                acc1[e] = fmaf(a1[3], wv[3], acc1[e]);
            }
            if (q < 3 || p == 0) { a0 = n0; a1 = n1; }
        }

        const float u0v = rscatter(acc0[0], acc0[1], acc0[2], acc0[3],
                                   acc0[4], acc0[5], acc0[6], acc0[7]);
        const float u1v = rscatter(acc1[0], acc1[1], acc1[2], acc1[3],
                                   acc1[4], acc1[5], acc1[6], acc1[7]);
        mylog = (g == 2 * p)     ? u0v : mylog;
        mylog = (g == 2 * p + 1) ? u1v : mylog;
    }

    // --- epilogue: softmax + top-2 within each 8-lane group (masks 1,2,4) ---
    // groups g>=4 compute on zeros (pe=1/8, no NaN); excluded from stores/sums
    float mx = mylog;
    mx = fmaxf(mx, __shfl_xor(mx, 1));
    mx = fmaxf(mx, __shfl_xor(mx, 2));
    mx = fmaxf(mx, __shfl_xor(mx, 4));
    float pe = expf(mylog - mx);
    float s = pe;
    s += __shfl_xor(s, 1); s += __shfl_xor(s, 2); s += __shfl_xor(s, 4);
    pe = pe / s;

    // top-1 (max, lowest index on ties — lax.top_k semantics)
    float v1 = pe; int i1 = eo;
#pragma unroll
    for (int m = 1; m <= 4; m <<= 1) {
        const float ov = __shfl_xor(v1, m);
        const int   oi = __shfl_xor(i1, m);
        const bool take = (ov > v1) || (ov == v1 && oi < i1);
        v1 = take ? ov : v1; i1 = take ? oi : i1;
    }
    // top-2: exclude winner (probs > 0 always, so -1 is a safe sentinel)
    float v2 = (eo == i1) ? -1.f : pe; int i2 = eo;
#pragma unroll
    for (int m = 1; m <= 4; m <<= 1) {
        const float ov = __shfl_xor(v2, m);
        const int   oi = __shfl_xor(i2, m);
        const bool take = (ov > v2) || (ov == v2 && oi < i2);
        v2 = take ? ov : v2; i2 = take ? oi : i2;
    }
    const float s12 = v1 + v2;
    const float d = (eo == i1) ? (v1 / s12) : ((eo == i2) ? (v2 / s12) : 0.f);

    // stores: owner lanes (g<4 i.e. lane<32): 128B contiguous per wave
    if (lane < 32) {
        dispatch[tok0 * E + lane]  = d;
        probs_out[tok0 * E + lane] = pe;
    }

    // per-wave slot sums: slot e = dispatch mass, slot 8+e = prob sum;
    // zero the non-owner groups before the cross-group butterfly
    float ds = (g < 4) ? d : 0.f, ps = (g < 4) ? pe : 0.f;
    ds += __shfl_xor(ds, 8);  ps += __shfl_xor(ps, 8);
    ds += __shfl_xor(ds, 16); ps += __shfl_xor(ps, 16);
    ds += __shfl_xor(ds, 32); ps += __shfl_xor(ps, 32);
    if (lane < 8) { red[wave][eo] = ds; red[wave][8 + eo] = ps; }
    __syncthreads();
    if (tid < 16) {
        float acc = 0.f;
#pragma unroll
        for (int wv = 0; wv < 8; ++wv) acc += red[wv][tid];
        partial[(size_t)tid * gridDim.x + blockIdx.x] = acc;   // slot-major
    }
}

// ---------------------------------------------------------------------------
// Kernel 2: reduce partials -> lb_loss; per-expert capacity enforcement
// (exact radix select, index-ordered ties). Early-exits when under capacity
// (always, in expectation: E[mass/expert]=4096 < 5120 -- insurance path).
// ---------------------------------------------------------------------------
__global__ __launch_bounds__(FBLK) void finalize_kernel(
    float* __restrict__ dispatch,
    const float* __restrict__ partial,
    int nb,
    float* __restrict__ lb_out,
    int N)
{
    const int e    = blockIdx.x;
    const int tid  = threadIdx.x;
    const int lane = tid & 63;
    const int wv   = tid >> 6;           // 16 waves -> 16 slots

    __shared__ float g[16];
    {
        float v = 0.f;
        for (int b = lane; b < nb; b += 64) v += partial[(size_t)wv * nb + b];
#pragma unroll
        for (int off = 32; off; off >>= 1) v += __shfl_xor(v, off);
        if (lane == 0) g[wv] = v;
    }
    __syncthreads();

    if (e == 0 && tid == 0) {
        float s = 0.f;
        for (int i = 0; i < E; ++i) s += g[i] * g[E + i];
        *lb_out = 0.01f * s / (float)N;
    }

    const float tpe = g[e];
    if (!(tpe > (float)CAP)) return;     // block-uniform

    __shared__ unsigned hist[256];
    __shared__ unsigned sh_prefix;
    __shared__ int sh_k;

    unsigned prefix = 0;
    int k = CAP;

    for (int round = 0; round < 4; ++round) {
        const int shift = 24 - 8 * round;
        for (int i = tid; i < 256; i += FBLK) hist[i] = 0;
        __syncthreads();
        const unsigned mhi = (round == 0) ? 0u : (0xFFFFFFFFu << (shift + 8));
        for (int i = tid; i < N; i += FBLK) {
            const unsigned bits = __float_as_uint(dispatch[(size_t)i * E + e]);
            if ((bits & mhi) == (prefix & mhi))
                atomicAdd(&hist[(bits >> shift) & 255u], 1u);
        }
        __syncthreads();
        if (tid == 0) {
            int cum = 0;
            int d = 255;
            for (; d > 0; --d) {
                const int h = (int)hist[d];
                if (cum + h >= k) break;
                cum += h;
            }
            sh_prefix = prefix | ((unsigned)d << shift);
            sh_k = k - cum;
        }
        __syncthreads();
        prefix = sh_prefix;
        k = sh_k;
        __syncthreads();
    }

    const unsigned T = prefix;
    const unsigned r = (unsigned)k;

    __shared__ unsigned wave_cnt[FBLK / 64];
    __shared__ unsigned running;
    if (tid == 0) running = 0;
    __syncthreads();

    for (int base = 0; base < N; base += FBLK) {
        const int i = base + tid;
        const unsigned bits = __float_as_uint(dispatch[(size_t)i * E + e]);
        const bool eq = (bits == T);
        const unsigned long long bal = __ballot(eq);
        if (lane == 0) wave_cnt[wv] = (unsigned)__popcll(bal);
        __syncthreads();
        unsigned before = running;
        for (int w = 0; w < wv; ++w) before += wave_cnt[w];
        const unsigned rank = before + (unsigned)__popcll(bal & ((1ull << lane) - 1ull));
        const bool keep = (bits > T) || (eq && rank < r);
        if (!keep) dispatch[(size_t)i * E + e] = 0.f;
        __syncthreads();
        if (tid == 0) {
            unsigned tot = 0;
            for (int w = 0; w < FBLK / 64; ++w) tot += wave_cnt[w];
            running += tot;
        }
        __syncthreads();
    }
}

// ---------------------------------------------------------------------------
extern "C" void kernel_launch(void* const* d_in, const int* in_sizes, int n_in,
                              void* d_out, int out_size, void* d_ws, size_t ws_size,
                              hipStream_t stream)
{
    const float* hs = (const float*)d_in[0];
    const float* rw = (const float*)d_in[1];
    const int n_tokens = in_sizes[0] / H;          // 32768

    float* dispatch = (float*)d_out;               // [N*E]
    float* lb       = dispatch + (size_t)n_tokens * E;
    float* probs    = lb + 1;                      // [N*E]
    float* partial  = (float*)d_ws;                // [16][nb] fp32, fully written

    const int nb = n_tokens / ((BLK / 64) * TPW);  // 1024 blocks, 32 tokens each
    router_kernel<<<nb, BLK, 0, stream>>>(hs, rw, dispatch, probs, partial);
    finalize_kernel<<<E, FBLK, 0, stream>>>(dispatch, partial, nb, lb, n_tokens);
}

// Round 10
// 198.846 us; speedup vs baseline: 1.0128x; 1.0128x over previous
//
#include <hip/hip_runtime.h>

#define H 1024
#define E 8
#define BLK 256
#define CAP 5120       // int(1.25 * 4096 * 8 / 8)
#define FBLK 1024
#define TPW 8          // tokens per wave

typedef float f32x4 __attribute__((ext_vector_type(4)));

// ---------------------------------------------------------------------------
// FINAL KERNEL — session-best configuration (R6, 197.4us total).
// Session findings (R0-R9):
//  * __launch_bounds__ arg2 sets VGPR cap = 256/arg2 on this toolchain
//    (5->48, 4->64, 2->128 measured). Caps below ~100 regs spilled this
//    design wholesale (114-170MB scratch round-trips, R1/R3/R4/R5).
//    arg2=2 (cap 128) is free: LDS 33KB caps occupancy at 4 blocks/CU anyway.
//  * Plateau analysis: total 197us = fixed harness ~136us (512MB poison
//    fill 78us + reset/launch machinery ~58us; stable across routers of
//    61-157us) + router ~61us + finalize ~5us. Router HBM floor = 21us
//    (134MB @ 6.3TB/s); effective 2.2TB/s. Four orthogonal levers (MLP
//    depth x2, LDS traffic x0.5, I$ x0.25, occupancy x2) all returned
//    exactly null; no pipe >45% (VALU 3.4us/CU, LDS 10us/CU, conflicts 0,
//    13x Little's-law margin) -> structural latency floor of the
//    load->FMA->shfl interleave at plain-HIP level.
// Design:
//  - w in LDS 32KB; lane l reads (e*1024+q*256+4l): conflict-free b128,
//    reused across 2 tokens.
//  - hs loads 1KB-contiguous per wave (lane l owns floats {4l+256q} of one
//    row); depth-2 token prefetch staggered through the q-loop.
//  - reduce-scatter (masks 1,2,4 keep/send; 8,16,32 add) -> lane 8g+e holds
//    logit(token g, expert e); 10 shfl/token.
//  - group-of-8 softmax/top2 butterflies, all 64 lanes active; stores
//    1 dword/lane, 256B contiguous per wave.
// ---------------------------------------------------------------------------
__global__ __launch_bounds__(BLK, 2) void router_kernel(
    const float* __restrict__ hs,
    const float* __restrict__ rw,
    float* __restrict__ dispatch,
    float* __restrict__ probs_out,
    float* __restrict__ partial)   // [16][nb] slot-major
{
    __shared__ float w_lds[E * H];   // 32 KB
    __shared__ float red[4][16];

    const int tid  = threadIdx.x;
    const int wave = tid >> 6;
    const int lane = tid & 63;
    const int g    = lane >> 3;      // token group within wave (0..7)
    const int eo   = lane & 7;       // owned expert
    const size_t tok0 = ((size_t)blockIdx.x * (BLK / 64) + wave) * TPW;
    const float* h0 = hs + tok0 * H + 4 * lane;

    // depth-2 token prefetch (8 x 1KB contiguous wave-loads), issued before
    // the w staging so the HBM round-trip overlaps it
    f32x4 A0[4], A1[4];
#pragma unroll
    for (int q = 0; q < 4; ++q) A0[q] = *(const f32x4*)(h0 + q * 256);
#pragma unroll
    for (int q = 0; q < 4; ++q) A1[q] = *(const f32x4*)(h0 + H + q * 256);

    for (int i = tid; i < E * H / 4; i += BLK)
        ((f32x4*)w_lds)[i] = ((const f32x4*)rw)[i];
    __syncthreads();

    const int b0 = lane & 1, b1 = (lane >> 1) & 1, b2 = (lane >> 2) & 1;

    // reduce-scatter over the 8-expert set (inputs by value, all-SSA after
    // inlining). Output: full dot for expert (lane&7), replicated over the
    // 8-lane groups.
    auto rscatter = [&](float a0, float a1, float a2, float a3,
                        float a4, float a5, float a6, float a7) -> float {
        float r0 = b0 ? a1 : a0, s0 = b0 ? a0 : a1;
        float r1 = b0 ? a3 : a2, s1 = b0 ? a2 : a3;
        float r2 = b0 ? a5 : a4, s2 = b0 ? a4 : a5;
        float r3 = b0 ? a7 : a6, s3 = b0 ? a6 : a7;
        r0 += __shfl_xor(s0, 1); r1 += __shfl_xor(s1, 1);
        r2 += __shfl_xor(s2, 1); r3 += __shfl_xor(s3, 1);
        float t0 = b1 ? r1 : r0, u0 = b1 ? r0 : r1;
        float t1 = b1 ? r3 : r2, u1 = b1 ? r2 : r3;
        t0 += __shfl_xor(u0, 2); t1 += __shfl_xor(u1, 2);
        float v = b2 ? t1 : t0, x = b2 ? t0 : t1;
        v += __shfl_xor(x, 4);
        v += __shfl_xor(v, 8);
        v += __shfl_xor(v, 16);
        v += __shfl_xor(v, 32);
        return v;                 // logit for expert 4*b2+2*b1+b0 = lane&7
    };

    float mylog = 0.f;            // latched logit for (token tok0+g, expert eo)
    const float* pnext = h0 + 2 * H;

#pragma unroll
    for (int t = 0; t < TPW; t += 2) {
        float acc0[E], acc1[E];
#pragma unroll
        for (int e = 0; e < E; ++e) { acc0[e] = 0.f; acc1[e] = 0.f; }

#pragma unroll
        for (int q = 0; q < 4; ++q) {
            const float* wb = w_lds + q * 256 + 4 * lane;
#pragma unroll
            for (int e = 0; e < E; ++e) {
                const f32x4 wv = *(const f32x4*)(wb + e * H);
                acc0[e] = fmaf(A0[q][0], wv[0], acc0[e]);
                acc0[e] = fmaf(A0[q][1], wv[1], acc0[e]);
                acc0[e] = fmaf(A0[q][2], wv[2], acc0[e]);
                acc0[e] = fmaf(A0[q][3], wv[3], acc0[e]);
                acc1[e] = fmaf(A1[q][0], wv[0], acc1[e]);
                acc1[e] = fmaf(A1[q][1], wv[1], acc1[e]);
                acc1[e] = fmaf(A1[q][2], wv[2], acc1[e]);
                acc1[e] = fmaf(A1[q][3], wv[3], acc1[e]);
            }
            // staggered depth-2 refill: A*[q] dead after this q-phase
            if (t + 2 < TPW) {
                A0[q] = *(const f32x4*)(pnext + q * 256);
                A1[q] = *(const f32x4*)(pnext + H + q * 256);
            }
        }
        if (t + 2 < TPW) pnext += 2 * H;

        const float u0v = rscatter(acc0[0], acc0[1], acc0[2], acc0[3],
                                   acc0[4], acc0[5], acc0[6], acc0[7]);
        const float u1v = rscatter(acc1[0], acc1[1], acc1[2], acc1[3],
                                   acc1[4], acc1[5], acc1[6], acc1[7]);
        mylog = (g == t)     ? u0v : mylog;
        mylog = (g == t + 1) ? u1v : mylog;
    }

    // --- epilogue: softmax + top-2 within each 8-lane group (masks 1,2,4) ---
    float mx = mylog;
    mx = fmaxf(mx, __shfl_xor(mx, 1));
    mx = fmaxf(mx, __shfl_xor(mx, 2));
    mx = fmaxf(mx, __shfl_xor(mx, 4));
    float pe = expf(mylog - mx);
    float s = pe;
    s += __shfl_xor(s, 1); s += __shfl_xor(s, 2); s += __shfl_xor(s, 4);
    pe = pe / s;

    // top-1 (max, lowest index on ties — lax.top_k semantics)
    float v1 = pe; int i1 = eo;
#pragma unroll
    for (int m = 1; m <= 4; m <<= 1) {
        const float ov = __shfl_xor(v1, m);
        const int   oi = __shfl_xor(i1, m);
        const bool take = (ov > v1) || (ov == v1 && oi < i1);
        v1 = take ? ov : v1; i1 = take ? oi : i1;
    }
    // top-2: exclude winner (probs > 0 always, so -1 is a safe sentinel)
    float v2 = (eo == i1) ? -1.f : pe; int i2 = eo;
#pragma unroll
    for (int m = 1; m <= 4; m <<= 1) {
        const float ov = __shfl_xor(v2, m);
        const int   oi = __shfl_xor(i2, m);
        const bool take = (ov > v2) || (ov == v2 && oi < i2);
        v2 = take ? ov : v2; i2 = take ? oi : i2;
    }
    const float s12 = v1 + v2;
    const float d = (eo == i1) ? (v1 / s12) : ((eo == i2) ? (v2 / s12) : 0.f);

    // stores: one dword/lane, 256B contiguous per wave
    dispatch[tok0 * E + lane]  = d;
    probs_out[tok0 * E + lane] = pe;

    // per-wave slot sums: slot e = dispatch mass, slot 8+e = prob sum
    float ds = d, ps = pe;
    ds += __shfl_xor(ds, 8);  ps += __shfl_xor(ps, 8);
    ds += __shfl_xor(ds, 16); ps += __shfl_xor(ps, 16);
    ds += __shfl_xor(ds, 32); ps += __shfl_xor(ps, 32);
    if (lane < 8) { red[wave][eo] = ds; red[wave][8 + eo] = ps; }
    __syncthreads();
    if (tid < 16) {
        const float acc = red[0][tid] + red[1][tid] + red[2][tid] + red[3][tid];
        partial[(size_t)tid * gridDim.x + blockIdx.x] = acc;   // slot-major
    }
}

// ---------------------------------------------------------------------------
// Kernel 2: reduce partials -> lb_loss; per-expert capacity enforcement
// (exact radix select, index-ordered ties). Early-exits when under capacity
// (always, in expectation: E[mass/expert]=4096 < 5120 -- insurance path).
// ---------------------------------------------------------------------------
__global__ __launch_bounds__(FBLK) void finalize_kernel(
    float* __restrict__ dispatch,
    const float* __restrict__ partial,
    int nb,
    float* __restrict__ lb_out,
    int N)
{
    const int e    = blockIdx.x;
    const int tid  = threadIdx.x;
    const int lane = tid & 63;
    const int wv   = tid >> 6;           // 16 waves -> 16 slots

    __shared__ float g[16];
    {
        float v = 0.f;
        for (int b = lane; b < nb; b += 64) v += partial[(size_t)wv * nb + b];
#pragma unroll
        for (int off = 32; off; off >>= 1) v += __shfl_xor(v, off);
        if (lane == 0) g[wv] = v;
    }
    __syncthreads();

    if (e == 0 && tid == 0) {
        float s = 0.f;
        for (int i = 0; i < E; ++i) s += g[i] * g[E + i];
        *lb_out = 0.01f * s / (float)N;
    }

    const float tpe = g[e];
    if (!(tpe > (float)CAP)) return;     // block-uniform

    __shared__ unsigned hist[256];
    __shared__ unsigned sh_prefix;
    __shared__ int sh_k;

    unsigned prefix = 0;
    int k = CAP;

    for (int round = 0; round < 4; ++round) {
        const int shift = 24 - 8 * round;
        for (int i = tid; i < 256; i += FBLK) hist[i] = 0;
        __syncthreads();
        const unsigned mhi = (round == 0) ? 0u : (0xFFFFFFFFu << (shift + 8));
        for (int i = tid; i < N; i += FBLK) {
            const unsigned bits = __float_as_uint(dispatch[(size_t)i * E + e]);
            if ((bits & mhi) == (prefix & mhi))
                atomicAdd(&hist[(bits >> shift) & 255u], 1u);
        }
        __syncthreads();
        if (tid == 0) {
            int cum = 0;
            int d = 255;
            for (; d > 0; --d) {
                const int h = (int)hist[d];
                if (cum + h >= k) break;
                cum += h;
            }
            sh_prefix = prefix | ((unsigned)d << shift);
            sh_k = k - cum;
        }
        __syncthreads();
        prefix = sh_prefix;
        k = sh_k;
        __syncthreads();
    }

    const unsigned T = prefix;
    const unsigned r = (unsigned)k;

    __shared__ unsigned wave_cnt[FBLK / 64];
    __shared__ unsigned running;
    if (tid == 0) running = 0;
    __syncthreads();

    for (int base = 0; base < N; base += FBLK) {
        const int i = base + tid;
        const unsigned bits = __float_as_uint(dispatch[(size_t)i * E + e]);
        const bool eq = (bits == T);
        const unsigned long long bal = __ballot(eq);
        if (lane == 0) wave_cnt[wv] = (unsigned)__popcll(bal);
        __syncthreads();
        unsigned before = running;
        for (int w = 0; w < wv; ++w) before += wave_cnt[w];
        const unsigned rank = before + (unsigned)__popcll(bal & ((1ull << lane) - 1ull));
        const bool keep = (bits > T) || (eq && rank < r);
        if (!keep) dispatch[(size_t)i * E + e] = 0.f;
        __syncthreads();
        if (tid == 0) {
            unsigned tot = 0;
            for (int w = 0; w < FBLK / 64; ++w) tot += wave_cnt[w];
            running += tot;
        }
        __syncthreads();
    }
}

// ---------------------------------------------------------------------------
extern "C" void kernel_launch(void* const* d_in, const int* in_sizes, int n_in,
                              void* d_out, int out_size, void* d_ws, size_t ws_size,
                              hipStream_t stream)
{
    const float* hs = (const float*)d_in[0];
    const float* rw = (const float*)d_in[1];
    const int n_tokens = in_sizes[0] / H;          // 32768

    float* dispatch = (float*)d_out;               // [N*E]
    float* lb       = dispatch + (size_t)n_tokens * E;
    float* probs    = lb + 1;                      // [N*E]
    float* partial  = (float*)d_ws;                // [16][nb] fp32, fully written

    const int nb = n_tokens / (4 * TPW);           // 1024 blocks, 32 tokens each
    router_kernel<<<nb, BLK, 0, stream>>>(hs, rw, dispatch, probs, partial);
    finalize_kernel<<<E, FBLK, 0, stream>>>(dispatch, partial, nb, lb, n_tokens);
}